// Round 1
// baseline (586.402 us; speedup 1.0000x reference)
//
#include <hip/hip_runtime.h>
#include <math.h>

// ---------------------------------------------------------------------------
// TemporalMambaBlock fused kernel (MI355X / gfx950)
// B=4, T=64, N=1024, H=64, INNER=128. 4096 independent sequences.
// One block (256 threads, 4 waves) per sequence; all GEMMs via
// v_mfma_f32_16x16x32_bf16; conv/scan/activations in fp32.
// ---------------------------------------------------------------------------

typedef __bf16 bf16x8 __attribute__((ext_vector_type(8)));
typedef float f32x4 __attribute__((ext_vector_type(4)));

#define LDA 72    // XA row stride (elems), K=64 + pad -> 2-way-bank-conflict-free b128 reads
#define LDW 136   // 128-wide bf16 rows + pad (272 B stride)
#define LDD 132   // scan buffers: pad so 4 row-group epilogue writes are conflict-free

// ws layout (ushort element offsets)
#define WIN_E 0                 // w_inT  [256][72]
#define WD_E  18432             // w_deltaT [128][136]
#define WSI_E 35840             // w_siT
#define WSO_E 53248             // w_soT
#define WOT_E 70656             // w_outT [64][136]
#define WS_END_E 79360
#define AS_BYTE (WS_END_E * 2)  // float a_s[128] after the bf16 region

__device__ inline unsigned short f2bf(float f) {
  unsigned int u = __float_as_uint(f);
  u += 0x7fffu + ((u >> 16) & 1u);   // RNE
  return (unsigned short)(u >> 16);
}
__device__ inline float bf2f(unsigned short s) {
  return __uint_as_float(((unsigned int)s) << 16);
}
__device__ inline float sigmoid_f(float x) {
  return __fdividef(1.f, 1.f + __expf(-x));
}
__device__ inline float tanh_fast(float x) {
  x = fminf(fmaxf(x, -15.f), 15.f);
  float e2 = __expf(2.f * x);
  return __fdividef(e2 - 1.f, e2 + 1.f);
}
__device__ inline float softplus_f(float x) {
  return (x > 15.f) ? x : log1pf(__expf(x));
}

// ---- weight prep: fp32 -> bf16, transposed to [out_col][k] with padded rows
__global__ __launch_bounds__(256) void prep_kernel(
    const float* __restrict__ w_in, const float* __restrict__ w_delta,
    const float* __restrict__ w_si, const float* __restrict__ w_so,
    const float* __restrict__ w_out, const float* __restrict__ a_log,
    unsigned short* __restrict__ wq, float* __restrict__ a_s) {
  int i = blockIdx.x * 256 + threadIdx.x;
  if (i < 16384) {                       // w_inT[c][k] = w_in[k][c], c<256,k<64
    int c = i >> 6, k = i & 63;
    wq[WIN_E + c * LDA + k] = f2bf(w_in[k * 256 + c]);
  } else if (i < 32768) {
    int j = i - 16384; int c2 = j >> 7, c1 = j & 127;
    wq[WD_E + c2 * LDW + c1] = f2bf(w_delta[c1 * 128 + c2]);
  } else if (i < 49152) {
    int j = i - 32768; int c2 = j >> 7, c1 = j & 127;
    wq[WSI_E + c2 * LDW + c1] = f2bf(w_si[c1 * 128 + c2]);
  } else if (i < 65536) {
    int j = i - 49152; int c2 = j >> 7, c1 = j & 127;
    wq[WSO_E + c2 * LDW + c1] = f2bf(w_so[c1 * 128 + c2]);
  } else if (i < 73728) {
    int j = i - 65536; int h = j >> 7, c = j & 127;
    wq[WOT_E + h * LDW + c] = f2bf(w_out[c * 64 + h]);
  } else if (i < 73856) {
    int c = i - 73728;
    a_s[c] = -log1pf(__expf(a_log[c]));  // a = -softplus(a_log)
  }
}

// ---- reg staging helpers (load early / store late so L2 latency hides)
template <int BYTES>
__device__ inline void stage_load(uint4* v, const unsigned short* src, int tid) {
  constexpr int NFULL = BYTES / 4096;
  const char* s = (const char*)src + tid * 16;
#pragma unroll
  for (int i = 0; i < NFULL; ++i) v[i] = *(const uint4*)(s + i * 4096);
  constexpr int REM = BYTES - NFULL * 4096;
  if constexpr (REM > 0) {
    if (tid * 16 < REM) v[NFULL] = *(const uint4*)(s + NFULL * 4096);
  }
}
template <int BYTES>
__device__ inline void stage_store(const uint4* v, unsigned short* dst, int tid) {
  constexpr int NFULL = BYTES / 4096;
  char* d = (char*)dst + tid * 16;
#pragma unroll
  for (int i = 0; i < NFULL; ++i) *(uint4*)(d + i * 4096) = v[i];
  constexpr int REM = BYTES - NFULL * 4096;
  if constexpr (REM > 0) {
    if (tid * 16 < REM) *(uint4*)(d + NFULL * 4096) = v[NFULL];
  }
}

// 64x32-per-wave GEMM over K=128: A rows from SP, B cols from WB (w^T layout)
__device__ inline void gemm_64x128(const unsigned short* SPl, const unsigned short* WBl,
                                   int lr, int lk, int wave, f32x4 acc[4][2]) {
  const f32x4 z = {0.f, 0.f, 0.f, 0.f};
#pragma unroll
  for (int mt = 0; mt < 4; ++mt) { acc[mt][0] = z; acc[mt][1] = z; }
#pragma unroll
  for (int ks = 0; ks < 4; ++ks) {
    bf16x8 af[4];
#pragma unroll
    for (int mt = 0; mt < 4; ++mt)
      af[mt] = *(const bf16x8*)(SPl + (mt * 16 + lr) * LDW + ks * 32 + lk);
#pragma unroll
    for (int ct = 0; ct < 2; ++ct) {
      bf16x8 bf = *(const bf16x8*)(WBl + (wave * 32 + ct * 16 + lr) * LDW + ks * 32 + lk);
#pragma unroll
      for (int mt = 0; mt < 4; ++mt)
        acc[mt][ct] = __builtin_amdgcn_mfma_f32_16x16x32_bf16(af[mt], bf, acc[mt][ct], 0, 0, 0);
    }
  }
}

__global__ __launch_bounds__(256) void mamba_main(
    const float* __restrict__ x, const float* __restrict__ b_in,
    const float* __restrict__ w_conv, const float* __restrict__ b_conv,
    const float* __restrict__ b_delta, const float* __restrict__ b_si,
    const float* __restrict__ b_so, const float* __restrict__ d_skip,
    const float* __restrict__ b_out, const unsigned short* __restrict__ wq,
    const float* __restrict__ a_s, float* __restrict__ out) {
  __shared__ unsigned short XA[64 * LDA];   // x tile, bf16
  __shared__ unsigned short WB[18432];      // staged weight (max 36864 B)
  __shared__ unsigned short SP[64 * LDW];   // signal_pre -> sigb -> hidden*sig(gate)
  __shared__ unsigned short GT[64 * LDD];   // gate (pre-sigmoid)
  __shared__ unsigned short DC[64 * LDD];   // decay
  __shared__ unsigned short SIb[64 * LDD];  // tanh(s_in)
  __shared__ unsigned short SOb[64 * LDD];  // tanh(s_out)

  const int tid = threadIdx.x;
  const int lane = tid & 63;
  const int wave = tid >> 6;
  const int lr = lane & 15;       // frag row (A) / col (B,D)
  const int lg = lane >> 4;       // lane group 0..3
  const int lk = lg * 8;          // k offset within a 32-k step

  const int seqid = blockIdx.x;
  const int bb = seqid >> 10;
  const int nn = seqid & 1023;

  uint4 sv[9];

  // ---------------- P0: stage w_inT; load x -> bf16 LDS ----------------
  stage_load<36864>(sv, wq + WIN_E, tid);
  {
    int t = tid >> 2;
    int c0 = (tid & 3) * 4;
    const float* xr = x + (((size_t)bb * 64 + t) * 1024 + nn) * 64;
#pragma unroll
    for (int i = 0; i < 4; ++i) {
      int c = c0 + i * 16;
      float4 v = *(const float4*)(xr + c);
      unsigned long long p = (unsigned long long)f2bf(v.x) |
                             ((unsigned long long)f2bf(v.y) << 16) |
                             ((unsigned long long)f2bf(v.z) << 32) |
                             ((unsigned long long)f2bf(v.w) << 48);
      *(unsigned long long*)(XA + t * LDA + c) = p;
    }
  }
  stage_store<36864>(sv, WB, tid);
  __syncthreads();

  // ---------------- P1: proj = X @ w_in  -> SP (signal), GT (gate) ----------------
  {
    f32x4 acc[4][4];
    const f32x4 z = {0.f, 0.f, 0.f, 0.f};
#pragma unroll
    for (int mt = 0; mt < 4; ++mt)
#pragma unroll
      for (int ct = 0; ct < 4; ++ct) acc[mt][ct] = z;
#pragma unroll
    for (int ks = 0; ks < 2; ++ks) {
      bf16x8 af[4];
#pragma unroll
      for (int mt = 0; mt < 4; ++mt)
        af[mt] = *(const bf16x8*)(XA + (mt * 16 + lr) * LDA + ks * 32 + lk);
#pragma unroll
      for (int ct = 0; ct < 4; ++ct) {
        bf16x8 bf = *(const bf16x8*)(WB + (wave * 64 + ct * 16 + lr) * LDA + ks * 32 + lk);
#pragma unroll
        for (int mt = 0; mt < 4; ++mt)
          acc[mt][ct] = __builtin_amdgcn_mfma_f32_16x16x32_bf16(af[mt], bf, acc[mt][ct], 0, 0, 0);
      }
    }
#pragma unroll
    for (int ct = 0; ct < 4; ++ct) {
      int col = wave * 64 + ct * 16 + lr;
      float bias = b_in[col];
#pragma unroll
      for (int mt = 0; mt < 4; ++mt) {
#pragma unroll
        for (int r = 0; r < 4; ++r) {
          int row = mt * 16 + lg * 4 + r;
          float v = acc[mt][ct][r] + bias;
          if (col < 128) SP[row * LDW + col] = f2bf(v);     // waves 0,1 (uniform)
          else GT[row * LDD + (col - 128)] = f2bf(v);       // waves 2,3
        }
      }
    }
  }
  __syncthreads();

  // ---------------- P2: causal depthwise conv (K=4) + silu, in place ----------------
  stage_load<34816>(sv, wq + WD_E, tid);  // prefetch w_deltaT under the conv
  {
    int c = tid & 127;
    int th = tid >> 7;
    int t0 = th * 32;
    float w0 = w_conv[c * 4 + 0], w1 = w_conv[c * 4 + 1];
    float w2 = w_conv[c * 4 + 2], w3 = w_conv[c * 4 + 3];
    float bc = b_conv[c];
    float h3 = 0.f, h2 = 0.f, h1 = 0.f;
    if (th) {
      h3 = bf2f(SP[(t0 - 3) * LDW + c]);
      h2 = bf2f(SP[(t0 - 2) * LDW + c]);
      h1 = bf2f(SP[(t0 - 1) * LDW + c]);
    }
    __syncthreads();  // boundary pre-values read before anyone overwrites
    for (int t = t0; t < t0 + 32; ++t) {
      float cur = bf2f(SP[t * LDW + c]);
      float s = w0 * h3 + w1 * h2 + w2 * h1 + w3 * cur + bc;
      float val = s * sigmoid_f(s);  // silu
      SP[t * LDW + c] = f2bf(val);
      h3 = h2; h2 = h1; h1 = cur;
    }
  }
  stage_store<34816>(sv, WB, tid);
  __syncthreads();

  // ---------------- P3a: delta -> decay ----------------
  stage_load<34816>(sv, wq + WSI_E, tid);
  {
    f32x4 acc[4][2];
    gemm_64x128(SP, WB, lr, lk, wave, acc);
#pragma unroll
    for (int ct = 0; ct < 2; ++ct) {
      int col = wave * 32 + ct * 16 + lr;
      float bias = b_delta[col];
      float av = a_s[col];
#pragma unroll
      for (int mt = 0; mt < 4; ++mt)
#pragma unroll
        for (int r = 0; r < 4; ++r) {
          int row = mt * 16 + lg * 4 + r;
          float d = softplus_f(acc[mt][ct][r] + bias);
          DC[row * LDD + col] = f2bf(__expf(d * av));
        }
    }
  }
  __syncthreads();
  stage_store<34816>(sv, WB, tid);
  __syncthreads();

  // ---------------- P3b: s_in = tanh ----------------
  stage_load<34816>(sv, wq + WSO_E, tid);
  {
    f32x4 acc[4][2];
    gemm_64x128(SP, WB, lr, lk, wave, acc);
#pragma unroll
    for (int ct = 0; ct < 2; ++ct) {
      int col = wave * 32 + ct * 16 + lr;
      float bias = b_si[col];
#pragma unroll
      for (int mt = 0; mt < 4; ++mt)
#pragma unroll
        for (int r = 0; r < 4; ++r) {
          int row = mt * 16 + lg * 4 + r;
          SIb[row * LDD + col] = f2bf(tanh_fast(acc[mt][ct][r] + bias));
        }
    }
  }
  __syncthreads();
  stage_store<34816>(sv, WB, tid);
  __syncthreads();

  // ---------------- P3c: s_out = tanh ----------------
  stage_load<17408>(sv, wq + WOT_E, tid);
  {
    f32x4 acc[4][2];
    gemm_64x128(SP, WB, lr, lk, wave, acc);
#pragma unroll
    for (int ct = 0; ct < 2; ++ct) {
      int col = wave * 32 + ct * 16 + lr;
      float bias = b_so[col];
#pragma unroll
      for (int mt = 0; mt < 4; ++mt)
#pragma unroll
        for (int r = 0; r < 4; ++r) {
          int row = mt * 16 + lg * 4 + r;
          SOb[row * LDD + col] = f2bf(tanh_fast(acc[mt][ct][r] + bias));
        }
    }
  }
  __syncthreads();
  stage_store<17408>(sv, WB, tid);

  // ---------------- P4: selective scan + gate, hidden -> SP (in place) ----------------
  if (tid < 128) {
    int c = tid;
    float dsk = d_skip[c];
    float st = 0.f;
#pragma unroll 4
    for (int t = 0; t < 64; ++t) {
      float dec = bf2f(DC[t * LDD + c]);
      float si = bf2f(SIb[t * LDD + c]);
      float so = bf2f(SOb[t * LDD + c]);
      float sg = bf2f(SP[t * LDW + c]);
      float g = bf2f(GT[t * LDD + c]);
      st = dec * st + si * sg;
      float h = so * st + dsk * sg;
      SP[t * LDW + c] = f2bf(h * sigmoid_f(g));
    }
  }
  __syncthreads();

  // ---------------- P5: out = hidden @ w_out + b_out ----------------
  {
    f32x4 acc[4];
    const f32x4 z = {0.f, 0.f, 0.f, 0.f};
#pragma unroll
    for (int mt = 0; mt < 4; ++mt) acc[mt] = z;
#pragma unroll
    for (int ks = 0; ks < 4; ++ks) {
      bf16x8 bf = *(const bf16x8*)(WB + (wave * 16 + lr) * LDW + ks * 32 + lk);
#pragma unroll
      for (int mt = 0; mt < 4; ++mt) {
        bf16x8 af = *(const bf16x8*)(SP + (mt * 16 + lr) * LDW + ks * 32 + lk);
        acc[mt] = __builtin_amdgcn_mfma_f32_16x16x32_bf16(af, bf, acc[mt], 0, 0, 0);
      }
    }
    int h = wave * 16 + lr;
    float bias = b_out[h];
#pragma unroll
    for (int mt = 0; mt < 4; ++mt)
#pragma unroll
      for (int r = 0; r < 4; ++r) {
        int t = mt * 16 + lg * 4 + r;
        out[(((size_t)bb * 64 + t) * 1024 + nn) * 64 + h] = acc[mt][r] + bias;
      }
  }
}

extern "C" void kernel_launch(void* const* d_in, const int* in_sizes, int n_in,
                              void* d_out, int out_size, void* d_ws, size_t ws_size,
                              hipStream_t stream) {
  const float* x = (const float*)d_in[0];
  const float* w_in = (const float*)d_in[1];
  const float* b_in = (const float*)d_in[2];
  const float* w_conv = (const float*)d_in[3];
  const float* b_conv = (const float*)d_in[4];
  const float* w_delta = (const float*)d_in[5];
  const float* b_delta = (const float*)d_in[6];
  const float* w_si = (const float*)d_in[7];
  const float* b_si = (const float*)d_in[8];
  const float* w_so = (const float*)d_in[9];
  const float* b_so = (const float*)d_in[10];
  const float* a_log = (const float*)d_in[11];
  const float* d_skip = (const float*)d_in[12];
  const float* w_out = (const float*)d_in[13];
  const float* b_out = (const float*)d_in[14];

  unsigned short* wq = (unsigned short*)d_ws;
  float* a_s = (float*)((char*)d_ws + AS_BYTE);

  hipLaunchKernelGGL(prep_kernel, dim3(289), dim3(256), 0, stream,
                     w_in, w_delta, w_si, w_so, w_out, a_log, wq, a_s);
  hipLaunchKernelGGL(mamba_main, dim3(4096), dim3(256), 0, stream,
                     x, b_in, w_conv, b_conv, b_delta, b_si, b_so, d_skip, b_out,
                     wq, a_s, (float*)d_out);
}

// Round 2
// 230.235 us; speedup vs baseline: 2.5470x; 2.5470x over previous
//
#include <hip/hip_runtime.h>
#include <math.h>

// ---------------------------------------------------------------------------
// TemporalMambaBlock fused kernel, round 2 (MI355X / gfx950)
// 4096 sequences (B*N), T=64 processed as 2 chunks of 32, H=64, INNER=128.
// One block (256 thr, 4 waves) per sequence, 42.75 KB LDS -> 3 blocks/CU.
// Weights pre-packed in MFMA-fragment-major layout; B operands loaded from
// global (L2-hot) straight into registers. All GEMMs: mfma_f32_16x16x32_bf16.
// ---------------------------------------------------------------------------

typedef __bf16 bf16x8 __attribute__((ext_vector_type(8)));
typedef float f32x4 __attribute__((ext_vector_type(4)));

#define LDX 72    // x tile stride (elems) inside XS
#define LDS_ 136  // stride for b128-read buffers (SP, DH)
#define LDN 132   // stride for scalar-access buffers (GT, SG, SIP view of XS)

// fragment-major weight arenas in d_ws (ushort element offsets)
#define WIN_E 0
#define WD_E 16384
#define WSI_E 32768
#define WSO_E 49152
#define WOT_E 65536
#define WQ_END 73728
#define AS_BYTE (WQ_END * 2)

__device__ inline unsigned short f2bf(float f) {
  unsigned int u = __float_as_uint(f);
  u += 0x7fffu + ((u >> 16) & 1u);  // RNE
  return (unsigned short)(u >> 16);
}
__device__ inline float bf2f(unsigned short s) {
  return __uint_as_float(((unsigned int)s) << 16);
}
__device__ inline float sigmoid_f(float x) { return __fdividef(1.f, 1.f + __expf(-x)); }
__device__ inline float tanh_fast(float x) {
  x = fminf(fmaxf(x, -15.f), 15.f);
  float e2 = __expf(2.f * x);
  return __fdividef(e2 - 1.f, e2 + 1.f);
}
__device__ inline float softplus_f(float x) { return (x > 15.f) ? x : log1pf(__expf(x)); }

// element (col,k) of a w^T matrix -> fragment-major offset.
// lane = (col&15) + 16*((k>>3)&3) reads bf16x8 at ((ks*nct+col/16)*64+lane)*8
__device__ inline int frag_off(int col, int k, int nct) {
  int ks = k >> 5, lg = (k >> 3) & 3, j = k & 7;
  return ((ks * nct + (col >> 4)) * 64 + ((col & 15) + (lg << 4))) * 8 + j;
}

// ---- weight prep: fp32 -> bf16, fragment-major; a = -softplus(a_log)
__global__ __launch_bounds__(256) void prep_kernel(
    const float* __restrict__ w_in, const float* __restrict__ w_delta,
    const float* __restrict__ w_si, const float* __restrict__ w_so,
    const float* __restrict__ w_out, const float* __restrict__ a_log,
    unsigned short* __restrict__ wq, float* __restrict__ a_s) {
  int i = blockIdx.x * 256 + threadIdx.x;
  if (i < 16384) {  // w_in [64][256]
    int col = i & 255, k = i >> 8;
    wq[WIN_E + frag_off(col, k, 16)] = f2bf(w_in[k * 256 + col]);
  } else if (i < 32768) {  // w_delta [128][128]
    int j = i - 16384;
    int col = j & 127, k = j >> 7;
    wq[WD_E + frag_off(col, k, 8)] = f2bf(w_delta[k * 128 + col]);
  } else if (i < 49152) {  // w_si
    int j = i - 32768;
    int col = j & 127, k = j >> 7;
    wq[WSI_E + frag_off(col, k, 8)] = f2bf(w_si[k * 128 + col]);
  } else if (i < 65536) {  // w_so
    int j = i - 49152;
    int col = j & 127, k = j >> 7;
    wq[WSO_E + frag_off(col, k, 8)] = f2bf(w_so[k * 128 + col]);
  } else if (i < 73728) {  // w_out [128][64]
    int j = i - 65536;
    int col = j & 63, k = j >> 6;
    wq[WOT_E + frag_off(col, k, 4)] = f2bf(w_out[k * 64 + col]);
  } else if (i < 73856) {
    int c = i - 73728;
    a_s[c] = -log1pf(__expf(a_log[c]));
  }
}

__global__ __launch_bounds__(256, 3) void mamba_main(
    const float* __restrict__ x, const float* __restrict__ b_in,
    const float* __restrict__ w_conv, const float* __restrict__ b_conv,
    const float* __restrict__ b_delta, const float* __restrict__ b_si,
    const float* __restrict__ b_so, const float* __restrict__ d_skip,
    const float* __restrict__ b_out, const unsigned short* __restrict__ wq,
    const float* __restrict__ a_s, float* __restrict__ out) {
  // buffer lifecycle per chunk:
  //  XS: x tile (stride 72)            -> SIP = tanh(s_in)*sg (stride 132)
  //  SP: signal pre-conv (136)         -> DC  = decay
  //  GT: gate (132)                    -> SKG = d_skip*sg*sig(g)  (in place)
  //  DH: csig = silu(conv) (136)       -> HG  = gated hidden
  //  SG: SOG = tanh(s_out)*sig(g) (132)
  __shared__ unsigned short XS[4224];
  __shared__ unsigned short SP[32 * LDS_];
  __shared__ unsigned short GT[32 * LDN];
  __shared__ unsigned short DH[32 * LDS_];
  __shared__ unsigned short SG[32 * LDN];

  const int tid = threadIdx.x;
  const int lane = tid & 63;
  const int wave = tid >> 6;
  const int lr = lane & 15;
  const int lg = lane >> 4;
  const int lk = lg << 3;

  const int bb = blockIdx.x >> 10;
  const int nn = blockIdx.x & 1023;

  const __bf16* wqb = (const __bf16*)wq;

  // ---- persistent per-thread constants (loaded once, L2-hot) ----
  float binv[4];
#pragma unroll
  for (int ct = 0; ct < 4; ++ct) binv[ct] = b_in[wave * 64 + ct * 16 + lr];
  float bdl[2], avv[2], bsv[2], bov2[2], dskv[2];
#pragma unroll
  for (int ct = 0; ct < 2; ++ct) {
    int c3 = wave * 32 + ct * 16 + lr;
    bdl[ct] = b_delta[c3];
    avv[ct] = a_s[c3];
    bsv[ct] = b_si[c3];
    bov2[ct] = b_so[c3];
    dskv[ct] = d_skip[c3];
  }
  const float bout = b_out[wave * 16 + lr];
  const int cc = tid & 127;
  const float cw0 = w_conv[cc * 4 + 0], cw1 = w_conv[cc * 4 + 1],
              cw2 = w_conv[cc * 4 + 2], cw3 = w_conv[cc * 4 + 3];
  const float cbc = b_conv[cc];
  float hs0 = 0.f, hs1 = 0.f, hs2 = 0.f;  // conv halo across chunks (tid<128)
  float st = 0.f;                          // scan state (tid<128)

  // ---- x chunk-0 load -> XS (bf16) ----
  {
    int tr = tid >> 3, c0 = (tid & 7) * 8;
    const float* xp = x + (((size_t)bb * 64 + tr) * 1024 + nn) * 64 + c0;
    float4 v0 = *(const float4*)xp;
    float4 v1 = *(const float4*)(xp + 4);
    uint4 pk;
    pk.x = f2bf(v0.x) | ((unsigned)f2bf(v0.y) << 16);
    pk.y = f2bf(v0.z) | ((unsigned)f2bf(v0.w) << 16);
    pk.z = f2bf(v1.x) | ((unsigned)f2bf(v1.y) << 16);
    pk.w = f2bf(v1.z) | ((unsigned)f2bf(v1.w) << 16);
    *(uint4*)(XS + tr * LDX + c0) = pk;
  }
  __syncthreads();

#pragma unroll
  for (int ch = 0; ch < 2; ++ch) {
    // ---------------- P1: proj = X @ w_in -> SP(signal), GT(gate) ----------------
    {
      bf16x8 bw[4][2];
#pragma unroll
      for (int ct = 0; ct < 4; ++ct)
#pragma unroll
        for (int ks = 0; ks < 2; ++ks)
          bw[ct][ks] = *(const bf16x8*)(wqb + WIN_E +
                                        (((ks << 4) + (wave << 2) + ct) * 64 + lane) * 8);
      bf16x8 ax[2][2];
#pragma unroll
      for (int mt = 0; mt < 2; ++mt)
#pragma unroll
        for (int ks = 0; ks < 2; ++ks)
          ax[mt][ks] = *(const bf16x8*)(XS + (mt * 16 + lr) * LDX + ks * 32 + lk);
      f32x4 acc[2][4];
      const f32x4 z = {0.f, 0.f, 0.f, 0.f};
#pragma unroll
      for (int mt = 0; mt < 2; ++mt)
#pragma unroll
        for (int ct = 0; ct < 4; ++ct) acc[mt][ct] = z;
#pragma unroll
      for (int ks = 0; ks < 2; ++ks)
#pragma unroll
        for (int ct = 0; ct < 4; ++ct)
#pragma unroll
          for (int mt = 0; mt < 2; ++mt)
            acc[mt][ct] = __builtin_amdgcn_mfma_f32_16x16x32_bf16(ax[mt][ks], bw[ct][ks],
                                                                  acc[mt][ct], 0, 0, 0);
#pragma unroll
      for (int ct = 0; ct < 4; ++ct) {
        int col = wave * 64 + ct * 16 + lr;
#pragma unroll
        for (int mt = 0; mt < 2; ++mt)
#pragma unroll
          for (int r = 0; r < 4; ++r) {
            int row = mt * 16 + lg * 4 + r;
            float v = acc[mt][ct][r] + binv[ct];
            if (col < 128) SP[row * LDS_ + col] = f2bf(v);
            else GT[row * LDN + col - 128] = f2bf(v);
          }
      }
    }
    __syncthreads();

    // -------- issue B(delta) loads (hide under conv); parallel FIR conv --------
    bf16x8 bd[2][4];
#pragma unroll
    for (int ct = 0; ct < 2; ++ct)
#pragma unroll
      for (int ks = 0; ks < 4; ++ks)
        bd[ct][ks] = *(const bf16x8*)(wqb + WD_E +
                                      (((ks << 3) + (wave << 1) + ct) * 64 + lane) * 8);
    {
      // conv is a 4-tap FIR (NOT a recurrence): 256 threads, 16 outputs each,
      // reading intact pre-conv SP, writing csig -> DH. Halo in registers.
      int th = tid >> 7;
      int t0 = th * 16;
      float in0[19];
      if (th == 0) {
        in0[0] = hs0; in0[1] = hs1; in0[2] = hs2;
      } else {
        in0[0] = bf2f(SP[13 * LDS_ + cc]);
        in0[1] = bf2f(SP[14 * LDS_ + cc]);
        in0[2] = bf2f(SP[15 * LDS_ + cc]);
      }
#pragma unroll
      for (int i = 3; i < 19; ++i) in0[i] = bf2f(SP[(t0 + i - 3) * LDS_ + cc]);
#pragma unroll
      for (int j = 0; j < 16; ++j) {
        float s = fmaf(cw0, in0[j],
                  fmaf(cw1, in0[j + 1], fmaf(cw2, in0[j + 2], fmaf(cw3, in0[j + 3], cbc))));
        DH[(t0 + j) * LDS_ + cc] = f2bf(s * sigmoid_f(s));
      }
      if (th == 0) {  // save pre-conv tail as next chunk's halo
        hs0 = bf2f(SP[29 * LDS_ + cc]);
        hs1 = bf2f(SP[30 * LDS_ + cc]);
        hs2 = bf2f(SP[31 * LDS_ + cc]);
      }
    }
    __syncthreads();

    // ---------------- P3: delta / s_in / s_out (no internal barriers) ----------------
    {
      bf16x8 af[2][4];
#pragma unroll
      for (int mt = 0; mt < 2; ++mt)
#pragma unroll
        for (int ks = 0; ks < 4; ++ks)
          af[mt][ks] = *(const bf16x8*)(DH + (mt * 16 + lr) * LDS_ + ks * 32 + lk);
      bf16x8 bs[2][4];  // s_in B frags, issued early to overlap with delta MFMA
#pragma unroll
      for (int ct = 0; ct < 2; ++ct)
#pragma unroll
        for (int ks = 0; ks < 4; ++ks)
          bs[ct][ks] = *(const bf16x8*)(wqb + WSI_E +
                                        (((ks << 3) + (wave << 1) + ct) * 64 + lane) * 8);
      const f32x4 z = {0.f, 0.f, 0.f, 0.f};
      f32x4 ad[2][2];
#pragma unroll
      for (int mt = 0; mt < 2; ++mt) { ad[mt][0] = z; ad[mt][1] = z; }
#pragma unroll
      for (int ks = 0; ks < 4; ++ks)
#pragma unroll
        for (int ct = 0; ct < 2; ++ct)
#pragma unroll
          for (int mt = 0; mt < 2; ++mt)
            ad[mt][ct] = __builtin_amdgcn_mfma_f32_16x16x32_bf16(af[mt][ks], bd[ct][ks],
                                                                 ad[mt][ct], 0, 0, 0);
      // decay -> SP (overwrites signal; conv already consumed it)
#pragma unroll
      for (int ct = 0; ct < 2; ++ct) {
        int col = wave * 32 + ct * 16 + lr;
#pragma unroll
        for (int mt = 0; mt < 2; ++mt)
#pragma unroll
          for (int r = 0; r < 4; ++r) {
            int row = mt * 16 + lg * 4 + r;
            float d = softplus_f(ad[mt][ct][r] + bdl[ct]);
            SP[row * LDS_ + col] = f2bf(__expf(d * avv[ct]));
          }
      }
      f32x4 as_[2][2];
#pragma unroll
      for (int mt = 0; mt < 2; ++mt) { as_[mt][0] = z; as_[mt][1] = z; }
#pragma unroll
      for (int ks = 0; ks < 4; ++ks)
#pragma unroll
        for (int ct = 0; ct < 2; ++ct)
#pragma unroll
          for (int mt = 0; mt < 2; ++mt)
            as_[mt][ct] = __builtin_amdgcn_mfma_f32_16x16x32_bf16(af[mt][ks], bs[ct][ks],
                                                                  as_[mt][ct], 0, 0, 0);
      bf16x8 bo_[2][4];  // s_out B frags, latency hides under s_in epilogue
#pragma unroll
      for (int ct = 0; ct < 2; ++ct)
#pragma unroll
        for (int ks = 0; ks < 4; ++ks)
          bo_[ct][ks] = *(const bf16x8*)(wqb + WSO_E +
                                         (((ks << 3) + (wave << 1) + ct) * 64 + lane) * 8);
      // SIP = tanh(s_in)*sg -> XS
#pragma unroll
      for (int ct = 0; ct < 2; ++ct) {
        int col = wave * 32 + ct * 16 + lr;
#pragma unroll
        for (int mt = 0; mt < 2; ++mt)
#pragma unroll
          for (int r = 0; r < 4; ++r) {
            int row = mt * 16 + lg * 4 + r;
            float sg = bf2f(DH[row * LDS_ + col]);
            XS[row * LDN + col] = f2bf(tanh_fast(as_[mt][ct][r] + bsv[ct]) * sg);
          }
      }
      f32x4 ao[2][2];
#pragma unroll
      for (int mt = 0; mt < 2; ++mt) { ao[mt][0] = z; ao[mt][1] = z; }
#pragma unroll
      for (int ks = 0; ks < 4; ++ks)
#pragma unroll
        for (int ct = 0; ct < 2; ++ct)
#pragma unroll
          for (int mt = 0; mt < 2; ++mt)
            ao[mt][ct] = __builtin_amdgcn_mfma_f32_16x16x32_bf16(af[mt][ks], bo_[ct][ks],
                                                                 ao[mt][ct], 0, 0, 0);
      // SOG = tanh(s_out)*sig(g) -> SG ; SKG = d_skip*sg*sig(g) -> GT (in place)
#pragma unroll
      for (int ct = 0; ct < 2; ++ct) {
        int col = wave * 32 + ct * 16 + lr;
#pragma unroll
        for (int mt = 0; mt < 2; ++mt)
#pragma unroll
          for (int r = 0; r < 4; ++r) {
            int row = mt * 16 + lg * 4 + r;
            float g = bf2f(GT[row * LDN + col]);
            float sgv = bf2f(DH[row * LDS_ + col]);
            float sig = sigmoid_f(g);
            SG[row * LDN + col] = f2bf(tanh_fast(ao[mt][ct][r] + bov2[ct]) * sig);
            GT[row * LDN + col] = f2bf(dskv[ct] * sgv * sig);
          }
      }
    }
    __syncthreads();

    // -------- issue B(out) + x chunk-1 prefetch; 32-step scan --------
    bf16x8 bw5[4];
#pragma unroll
    for (int ks = 0; ks < 4; ++ks)
      bw5[ks] = *(const bf16x8*)(wqb + WOT_E + (((ks << 2) + wave) * 64 + lane) * 8);
    float4 xv0, xv1;
    const int xtr = tid >> 3, xc0 = (tid & 7) * 8;
    if (ch == 0) {
      const float* xp = x + (((size_t)bb * 64 + 32 + xtr) * 1024 + nn) * 64 + xc0;
      xv0 = *(const float4*)xp;
      xv1 = *(const float4*)(xp + 4);
    }
    if (tid < 128) {
      // loads hit SP/XS/SG/GT, stores hit DH -> no aliasing, loads hoist above
      // the serial fma chain.
#pragma unroll
      for (int t = 0; t < 32; ++t) {
        float dec = bf2f(SP[t * LDS_ + cc]);
        float sip = bf2f(XS[t * LDN + cc]);
        float sog = bf2f(SG[t * LDN + cc]);
        float skg = bf2f(GT[t * LDN + cc]);
        st = fmaf(dec, st, sip);
        DH[t * LDS_ + cc] = f2bf(fmaf(sog, st, skg));
      }
    }
    __syncthreads();

    // ---------------- P5: out = HG @ w_out + b_out ----------------
    {
      bf16x8 ah[2][4];
#pragma unroll
      for (int mt = 0; mt < 2; ++mt)
#pragma unroll
        for (int ks = 0; ks < 4; ++ks)
          ah[mt][ks] = *(const bf16x8*)(DH + (mt * 16 + lr) * LDS_ + ks * 32 + lk);
      const f32x4 z = {0.f, 0.f, 0.f, 0.f};
      f32x4 a5[2];
      a5[0] = z; a5[1] = z;
#pragma unroll
      for (int ks = 0; ks < 4; ++ks)
#pragma unroll
        for (int mt = 0; mt < 2; ++mt)
          a5[mt] = __builtin_amdgcn_mfma_f32_16x16x32_bf16(ah[mt][ks], bw5[ks], a5[mt], 0, 0, 0);
      size_t ob = (((size_t)bb * 64 + ch * 32) * 1024 + nn) * 64 + wave * 16 + lr;
#pragma unroll
      for (int mt = 0; mt < 2; ++mt)
#pragma unroll
        for (int r = 0; r < 4; ++r) {
          int row = mt * 16 + lg * 4 + r;
          out[ob + (size_t)row * 65536] = a5[mt][r] + bout;
        }
      if (ch == 0) {  // write prefetched x chunk-1 into XS (SIP already consumed)
        uint4 pk;
        pk.x = f2bf(xv0.x) | ((unsigned)f2bf(xv0.y) << 16);
        pk.y = f2bf(xv0.z) | ((unsigned)f2bf(xv0.w) << 16);
        pk.z = f2bf(xv1.x) | ((unsigned)f2bf(xv1.y) << 16);
        pk.w = f2bf(xv1.z) | ((unsigned)f2bf(xv1.w) << 16);
        *(uint4*)(XS + xtr * LDX + xc0) = pk;
      }
    }
    __syncthreads();
  }
}

extern "C" void kernel_launch(void* const* d_in, const int* in_sizes, int n_in,
                              void* d_out, int out_size, void* d_ws, size_t ws_size,
                              hipStream_t stream) {
  const float* x = (const float*)d_in[0];
  const float* w_in = (const float*)d_in[1];
  const float* b_in = (const float*)d_in[2];
  const float* w_conv = (const float*)d_in[3];
  const float* b_conv = (const float*)d_in[4];
  const float* w_delta = (const float*)d_in[5];
  const float* b_delta = (const float*)d_in[6];
  const float* w_si = (const float*)d_in[7];
  const float* b_si = (const float*)d_in[8];
  const float* w_so = (const float*)d_in[9];
  const float* b_so = (const float*)d_in[10];
  const float* a_log = (const float*)d_in[11];
  const float* d_skip = (const float*)d_in[12];
  const float* w_out = (const float*)d_in[13];
  const float* b_out = (const float*)d_in[14];

  unsigned short* wq = (unsigned short*)d_ws;
  float* a_s = (float*)((char*)d_ws + AS_BYTE);

  hipLaunchKernelGGL(prep_kernel, dim3(289), dim3(256), 0, stream,
                     w_in, w_delta, w_si, w_so, w_out, a_log, wq, a_s);
  hipLaunchKernelGGL(mamba_main, dim3(4096), dim3(256), 0, stream,
                     x, b_in, w_conv, b_conv, b_delta, b_si, b_so, d_skip, b_out,
                     wq, a_s, (float*)d_out);
}

// Round 3
// 121.921 us; speedup vs baseline: 4.8097x; 1.8884x over previous
//
#include <hip/hip_runtime.h>
#include <math.h>

// ---------------------------------------------------------------------------
// TemporalMambaBlock fused kernel, round 3 (MI355X / gfx950)
// 4096 sequences, T=64 as 2 chunks of 32, H=64, INNER=128.
// One block (256 thr, 4 waves) per sequence. Conv AND selective scan run in
// registers (shuffle-based); only csig / sig(gate) / hidden round-trip LDS.
// All GEMMs: v_mfma_f32_16x16x32_bf16 with fragment-major weight arenas.
// ---------------------------------------------------------------------------

typedef __bf16 bf16x8 __attribute__((ext_vector_type(8)));
typedef float f32x4 __attribute__((ext_vector_type(4)));

// fragment-major weight arenas in d_ws (bf16 element offsets)
#define WIN_E 0
#define WD_E 16384
#define WSI_E 32768
#define WSO_E 49152
#define WOT_E 65536
#define WQ_END 73728
#define AS_BYTE (WQ_END * 2)

__device__ inline float sigm(float x) {
  return __builtin_amdgcn_rcpf(1.f + __expf(-x));
}
__device__ inline float tanh_c(float x) {  // 1 - 2/(e^2x+1); correct limits at +-inf
  return fmaf(-2.f, __builtin_amdgcn_rcpf(__expf(2.f * x) + 1.f), 1.f);
}

// element (col,k) of a w^T matrix -> fragment-major offset.
__device__ inline int frag_off(int col, int k, int nct) {
  int ks = k >> 5, lgk = (k >> 3) & 3, j = k & 7;
  return ((ks * nct + (col >> 4)) * 64 + ((col & 15) + (lgk << 4))) * 8 + j;
}

__global__ __launch_bounds__(256) void prep_kernel(
    const float* __restrict__ w_in, const float* __restrict__ w_delta,
    const float* __restrict__ w_si, const float* __restrict__ w_so,
    const float* __restrict__ w_out, const float* __restrict__ a_log,
    __bf16* __restrict__ wq, float* __restrict__ a_s) {
  int i = blockIdx.x * 256 + threadIdx.x;
  if (i < 16384) {  // w_in [64][256]
    int col = i & 255, k = i >> 8;
    wq[WIN_E + frag_off(col, k, 16)] = (__bf16)w_in[k * 256 + col];
  } else if (i < 32768) {  // w_delta [128][128]
    int j = i - 16384, col = j & 127, k = j >> 7;
    wq[WD_E + frag_off(col, k, 8)] = (__bf16)w_delta[k * 128 + col];
  } else if (i < 49152) {
    int j = i - 32768, col = j & 127, k = j >> 7;
    wq[WSI_E + frag_off(col, k, 8)] = (__bf16)w_si[k * 128 + col];
  } else if (i < 65536) {
    int j = i - 49152, col = j & 127, k = j >> 7;
    wq[WSO_E + frag_off(col, k, 8)] = (__bf16)w_so[k * 128 + col];
  } else if (i < 73728) {  // w_out [128][64]
    int j = i - 65536, col = j & 63, k = j >> 6;
    wq[WOT_E + frag_off(col, k, 4)] = (__bf16)w_out[k * 64 + col];
  } else if (i < 73856) {
    int c = i - 73728;
    a_s[c] = -log1pf(__expf(a_log[c]));
  }
}

__global__ __launch_bounds__(256, 3) void mamba_main(
    const float* __restrict__ x, const float* __restrict__ b_in,
    const float* __restrict__ w_conv, const float* __restrict__ b_conv,
    const float* __restrict__ b_delta, const float* __restrict__ b_si,
    const float* __restrict__ b_so, const float* __restrict__ d_skip,
    const float* __restrict__ b_out, const __bf16* __restrict__ wqb,
    const float* __restrict__ a_s, float* __restrict__ out) {
  __shared__ __bf16 XS[32 * 72];   // x tile (b128-readable, stride 72)
  __shared__ __bf16 GT[32 * 132];  // sig(gate)
  __shared__ __bf16 DH[32 * 136];  // csig = silu(conv(signal))
  __shared__ __bf16 HG[32 * 136];  // gated hidden (P5 A operand)

  const int tid = threadIdx.x;
  const int lane = tid & 63;
  const int wave = tid >> 6;
  const int lr = lane & 15;
  const int lg = lane >> 4;
  const int lk = lg << 3;
  const int bb = blockIdx.x >> 10;
  const int nn = blockIdx.x & 1023;

  // ---- per-thread constants (L2-hot) ----
  float bsig[2], bgat[2], bdl[2], avv[2], bsv[2], bov[2], dskv[2], cbc[2];
  float cw0[2], cw1[2], cw2[2], cw3[2];
#pragma unroll
  for (int ct = 0; ct < 2; ++ct) {
    int sc = wave * 32 + ct * 16 + lr;  // this thread's inner col for ct
    bsig[ct] = b_in[sc];
    bgat[ct] = b_in[128 + sc];
    bdl[ct] = b_delta[sc];
    avv[ct] = fminf(a_s[sc], -1e-30f);  // guard a==0 -> decay 1 (avoid 0*inf)
    bsv[ct] = b_si[sc];
    bov[ct] = b_so[sc];
    dskv[ct] = d_skip[sc];
    cw0[ct] = w_conv[sc * 4 + 0];
    cw1[ct] = w_conv[sc * 4 + 1];
    cw2[ct] = w_conv[sc * 4 + 2];
    cw3[ct] = w_conv[sc * 4 + 3];
    cbc[ct] = b_conv[sc];
  }
  const float bout = b_out[wave * 16 + lr];

  float car1[2] = {0.f, 0.f}, car2[2] = {0.f, 0.f}, car3[2] = {0.f, 0.f};
  float C[2] = {0.f, 0.f};  // scan carry per ct-col

  // ---- x chunk-0 -> XS ----
  const int xtr = tid >> 3, xc0 = (tid & 7) * 8;
  {
    const float* xp = x + (((size_t)bb * 64 + xtr) * 1024 + nn) * 64 + xc0;
    float4 v0 = *(const float4*)xp;
    float4 v1 = *(const float4*)(xp + 4);
    bf16x8 pk;
    pk[0] = (__bf16)v0.x; pk[1] = (__bf16)v0.y; pk[2] = (__bf16)v0.z; pk[3] = (__bf16)v0.w;
    pk[4] = (__bf16)v1.x; pk[5] = (__bf16)v1.y; pk[6] = (__bf16)v1.z; pk[7] = (__bf16)v1.w;
    *(bf16x8*)(XS + xtr * 72 + xc0) = pk;
  }
  __syncthreads();

#pragma unroll
  for (int ch = 0; ch < 2; ++ch) {
    // ================= P1: proj GEMM =================
    const int cbs[4] = {2 * wave, 2 * wave + 1, 8 + 2 * wave, 9 + 2 * wave};
    bf16x8 bw[4][2];
#pragma unroll
    for (int ct = 0; ct < 4; ++ct)
#pragma unroll
      for (int ks = 0; ks < 2; ++ks)
        bw[ct][ks] = *(const bf16x8*)(wqb + WIN_E + (((ks << 4) + cbs[ct]) * 64 + lane) * 8);
    // x chunk-1 prefetch (issue early; write after BARRIER_A)
    float4 xv0, xv1;
    if (ch == 0) {
      const float* xp = x + (((size_t)bb * 64 + 32 + xtr) * 1024 + nn) * 64 + xc0;
      xv0 = *(const float4*)xp;
      xv1 = *(const float4*)(xp + 4);
    }
    bf16x8 ax[2][2];
#pragma unroll
    for (int mt = 0; mt < 2; ++mt)
#pragma unroll
      for (int ks = 0; ks < 2; ++ks)
        ax[mt][ks] = *(const bf16x8*)(XS + (mt * 16 + lr) * 72 + ks * 32 + lk);
    f32x4 acc[2][4];
    const f32x4 z = {0.f, 0.f, 0.f, 0.f};
#pragma unroll
    for (int mt = 0; mt < 2; ++mt)
#pragma unroll
      for (int ct = 0; ct < 4; ++ct) acc[mt][ct] = z;
#pragma unroll
    for (int ks = 0; ks < 2; ++ks)
#pragma unroll
      for (int ct = 0; ct < 4; ++ct)
#pragma unroll
        for (int mt = 0; mt < 2; ++mt)
          acc[mt][ct] = __builtin_amdgcn_mfma_f32_16x16x32_bf16(ax[mt][ks], bw[ct][ks],
                                                                acc[mt][ct], 0, 0, 0);
    // ---- gate: sig(g) -> GT (bf16) ----
#pragma unroll
    for (int ct = 0; ct < 2; ++ct) {
      int gcol = wave * 32 + ct * 16 + lr;
#pragma unroll
      for (int mt = 0; mt < 2; ++mt)
#pragma unroll
        for (int r = 0; r < 4; ++r)
          GT[(mt * 16 + lg * 4 + r) * 132 + gcol] = (__bf16)sigm(acc[mt][ct + 2][r] + bgat[ct]);
    }
    // ---- conv (4-tap FIR) in registers; silu -> DH ----
#pragma unroll
    for (int ct = 0; ct < 2; ++ct) {
      int col = wave * 32 + ct * 16 + lr;
      float s0 = acc[0][ct][0] + bsig[ct], s1 = acc[0][ct][1] + bsig[ct];
      float s2 = acc[0][ct][2] + bsig[ct], s3 = acc[0][ct][3] + bsig[ct];
      float t0 = acc[1][ct][0] + bsig[ct], t1 = acc[1][ct][1] + bsig[ct];
      float t2 = acc[1][ct][2] + bsig[ct], t3 = acc[1][ct][3] + bsig[ct];
      // mt0 predecessors: rows base-1,-2,-3 = lg-1's s3,s2,s1 (or chunk carry)
      float a3 = __shfl_up(s3, 16), a2 = __shfl_up(s2, 16), a1 = __shfl_up(s1, 16);
      float p1 = lg ? a3 : car1[ct];
      float p2 = lg ? a2 : car2[ct];
      float p3 = lg ? a1 : car3[ct];
      // mt1 predecessors: lg-1's t3,t2,t1; lg==0 takes rows 15,14,13 = lg3's s3,s2,s1
      float b3 = __shfl_up(t3, 16), b2 = __shfl_up(t2, 16), b1 = __shfl_up(t1, 16);
      float q15 = __shfl(s3, lr + 48), q14 = __shfl(s2, lr + 48), q13 = __shfl(s1, lr + 48);
      float e1 = lg ? b3 : q15;
      float e2 = lg ? b2 : q14;
      float e3 = lg ? b1 : q13;
      car1[ct] = __shfl(t3, lr + 48);  // rows 31,30,29 for next chunk
      car2[ct] = __shfl(t2, lr + 48);
      car3[ct] = __shfl(t1, lr + 48);
      float c0 = fmaf(cw0[ct], p3, fmaf(cw1[ct], p2, fmaf(cw2[ct], p1, fmaf(cw3[ct], s0, cbc[ct]))));
      float c1 = fmaf(cw0[ct], p2, fmaf(cw1[ct], p1, fmaf(cw2[ct], s0, fmaf(cw3[ct], s1, cbc[ct]))));
      float c2 = fmaf(cw0[ct], p1, fmaf(cw1[ct], s0, fmaf(cw2[ct], s1, fmaf(cw3[ct], s2, cbc[ct]))));
      float c3 = fmaf(cw0[ct], s0, fmaf(cw1[ct], s1, fmaf(cw2[ct], s2, fmaf(cw3[ct], s3, cbc[ct]))));
      float d0 = fmaf(cw0[ct], e3, fmaf(cw1[ct], e2, fmaf(cw2[ct], e1, fmaf(cw3[ct], t0, cbc[ct]))));
      float d1 = fmaf(cw0[ct], e2, fmaf(cw1[ct], e1, fmaf(cw2[ct], t0, fmaf(cw3[ct], t1, cbc[ct]))));
      float d2 = fmaf(cw0[ct], e1, fmaf(cw1[ct], t0, fmaf(cw2[ct], t1, fmaf(cw3[ct], t2, cbc[ct]))));
      float d3 = fmaf(cw0[ct], t0, fmaf(cw1[ct], t1, fmaf(cw2[ct], t2, fmaf(cw3[ct], t3, cbc[ct]))));
      DH[(lg * 4 + 0) * 136 + col] = (__bf16)(c0 * sigm(c0));
      DH[(lg * 4 + 1) * 136 + col] = (__bf16)(c1 * sigm(c1));
      DH[(lg * 4 + 2) * 136 + col] = (__bf16)(c2 * sigm(c2));
      DH[(lg * 4 + 3) * 136 + col] = (__bf16)(c3 * sigm(c3));
      DH[(16 + lg * 4 + 0) * 136 + col] = (__bf16)(d0 * sigm(d0));
      DH[(16 + lg * 4 + 1) * 136 + col] = (__bf16)(d1 * sigm(d1));
      DH[(16 + lg * 4 + 2) * 136 + col] = (__bf16)(d2 * sigm(d2));
      DH[(16 + lg * 4 + 3) * 136 + col] = (__bf16)(d3 * sigm(d3));
    }
    __syncthreads();  // BARRIER_A: DH/GT ready, XS free

    // ================= P3: delta/s_in/s_out GEMMs + in-register scan =================
    bf16x8 af[2][4];
#pragma unroll
    for (int mt = 0; mt < 2; ++mt)
#pragma unroll
      for (int ks = 0; ks < 4; ++ks)
        af[mt][ks] = *(const bf16x8*)(DH + (mt * 16 + lr) * 136 + ks * 32 + lk);
    if (ch == 0) {  // land x chunk-1
      bf16x8 pk;
      pk[0] = (__bf16)xv0.x; pk[1] = (__bf16)xv0.y; pk[2] = (__bf16)xv0.z; pk[3] = (__bf16)xv0.w;
      pk[4] = (__bf16)xv1.x; pk[5] = (__bf16)xv1.y; pk[6] = (__bf16)xv1.z; pk[7] = (__bf16)xv1.w;
      *(bf16x8*)(XS + xtr * 72 + xc0) = pk;
    }
#pragma unroll
    for (int ct = 0; ct < 2; ++ct) {
      const int col = wave * 32 + ct * 16 + lr;
      const int cb = 2 * wave + ct;
      const f32x4 zz = {0.f, 0.f, 0.f, 0.f};
      // --- delta GEMM -> decay (f32 regs)
      bf16x8 bfr[4];
#pragma unroll
      for (int ks = 0; ks < 4; ++ks)
        bfr[ks] = *(const bf16x8*)(wqb + WD_E + (((ks << 3) + cb) * 64 + lane) * 8);
      f32x4 ad[2] = {zz, zz};
#pragma unroll
      for (int ks = 0; ks < 4; ++ks)
#pragma unroll
        for (int mt = 0; mt < 2; ++mt)
          ad[mt] = __builtin_amdgcn_mfma_f32_16x16x32_bf16(af[mt][ks], bfr[ks], ad[mt], 0, 0, 0);
      float dec[2][4];
#pragma unroll
      for (int mt = 0; mt < 2; ++mt)
#pragma unroll
        for (int r = 0; r < 4; ++r) {
          float xd = ad[mt][r] + bdl[ct];
          // decay = (1+e^xd)^a ; inf-safe (xd>>0 -> 0, xd<<0 -> 1)
          dec[mt][r] = __expf(avv[ct] * __logf(1.f + __expf(xd)));
        }
      // --- s_in GEMM -> u = tanh(.)*sg
#pragma unroll
      for (int ks = 0; ks < 4; ++ks)
        bfr[ks] = *(const bf16x8*)(wqb + WSI_E + (((ks << 3) + cb) * 64 + lane) * 8);
      f32x4 as_[2] = {zz, zz};
#pragma unroll
      for (int ks = 0; ks < 4; ++ks)
#pragma unroll
        for (int mt = 0; mt < 2; ++mt)
          as_[mt] = __builtin_amdgcn_mfma_f32_16x16x32_bf16(af[mt][ks], bfr[ks], as_[mt], 0, 0, 0);
      float sg[2][4], u[2][4];
#pragma unroll
      for (int mt = 0; mt < 2; ++mt)
#pragma unroll
        for (int r = 0; r < 4; ++r) {
          sg[mt][r] = (float)DH[(mt * 16 + lg * 4 + r) * 136 + col];
          u[mt][r] = tanh_c(as_[mt][r] + bsv[ct]) * sg[mt][r];
        }
      // --- local 4-step scans (partials p*, prefix decay products Q*)
      float p0 = u[0][0];
      float p1s = fmaf(dec[0][1], p0, u[0][1]);
      float p2s = fmaf(dec[0][2], p1s, u[0][2]);
      float p3s = fmaf(dec[0][3], p2s, u[0][3]);
      float Q0 = dec[0][0], Q1 = Q0 * dec[0][1], Q2 = Q1 * dec[0][2], Q3 = Q2 * dec[0][3];
      float r0 = u[1][0];
      float r1s = fmaf(dec[1][1], r0, u[1][1]);
      float r2s = fmaf(dec[1][2], r1s, u[1][2]);
      float r3s = fmaf(dec[1][3], r2s, u[1][3]);
      float S0 = dec[1][0], S1 = S0 * dec[1][1], S2 = S1 * dec[1][2], S3 = S2 * dec[1][3];
      // --- s_out GEMM -> tao
#pragma unroll
      for (int ks = 0; ks < 4; ++ks)
        bfr[ks] = *(const bf16x8*)(wqb + WSO_E + (((ks << 3) + cb) * 64 + lane) * 8);
      f32x4 ao[2] = {zz, zz};
#pragma unroll
      for (int ks = 0; ks < 4; ++ks)
#pragma unroll
        for (int mt = 0; mt < 2; ++mt)
          ao[mt] = __builtin_amdgcn_mfma_f32_16x16x32_bf16(af[mt][ks], bfr[ks], ao[mt], 0, 0, 0);
      float tao[2][4];
#pragma unroll
      for (int mt = 0; mt < 2; ++mt)
#pragma unroll
        for (int r = 0; r < 4; ++r) tao[mt][r] = tanh_c(ao[mt][r] + bov[ct]);
      // --- Hillis-Steele combine over 8 segments (4 lg x 2 mt), pairs (P,L)
      float Pa = Q3, La = p3s;  // mt0 segment summary
      float shp = __shfl_up(Pa, 16), shl = __shfl_up(La, 16);
      float Pa1 = (lg >= 1) ? Pa * shp : Pa;
      float La1 = (lg >= 1) ? fmaf(Pa, shl, La) : La;
      shp = __shfl_up(Pa1, 32); shl = __shfl_up(La1, 32);
      float Pa2 = (lg >= 2) ? Pa1 * shp : Pa1;
      float La2 = (lg >= 2) ? fmaf(Pa1, shl, La1) : La1;
      shp = __shfl_up(Pa2, 16); shl = __shfl_up(La2, 16);
      float Sin0 = lg ? fmaf(shp, C[ct], shl) : C[ct];
      float Pb = __shfl(Pa2, lr + 48), Lb = __shfl(La2, lr + 48);
      float T0 = fmaf(Pb, C[ct], Lb);  // state entering mt1 rows
      float Pc = S3, Lc = r3s;  // mt1 segment summary
      shp = __shfl_up(Pc, 16); shl = __shfl_up(Lc, 16);
      float Pc1 = (lg >= 1) ? Pc * shp : Pc;
      float Lc1 = (lg >= 1) ? fmaf(Pc, shl, Lc) : Lc;
      shp = __shfl_up(Pc1, 32); shl = __shfl_up(Lc1, 32);
      float Pc2 = (lg >= 2) ? Pc1 * shp : Pc1;
      float Lc2 = (lg >= 2) ? fmaf(Pc1, shl, Lc1) : Lc1;
      shp = __shfl_up(Pc2, 16); shl = __shfl_up(Lc2, 16);
      float Sin1 = lg ? fmaf(shp, T0, shl) : T0;
      float Pd = __shfl(Pc2, lr + 48), Ld = __shfl(Lc2, lr + 48);
      C[ct] = fmaf(Pd, T0, Ld);  // carry to next chunk
      // --- apply: st = partial + Q*Sin ; h = sig * (tao*st + dsk*sg) -> HG
      float st00 = fmaf(Q0, Sin0, p0);
      float st01 = fmaf(Q1, Sin0, p1s);
      float st02 = fmaf(Q2, Sin0, p2s);
      float st03 = fmaf(Q3, Sin0, p3s);
      float st10 = fmaf(S0, Sin1, r0);
      float st11 = fmaf(S1, Sin1, r1s);
      float st12 = fmaf(S2, Sin1, r2s);
      float st13 = fmaf(S3, Sin1, r3s);
      float stv[2][4] = {{st00, st01, st02, st03}, {st10, st11, st12, st13}};
#pragma unroll
      for (int mt = 0; mt < 2; ++mt)
#pragma unroll
        for (int r = 0; r < 4; ++r) {
          int row = mt * 16 + lg * 4 + r;
          float sigv = (float)GT[row * 132 + col];
          float h = sigv * fmaf(tao[mt][r], stv[mt][r], dskv[ct] * sg[mt][r]);
          HG[row * 136 + col] = (__bf16)h;
        }
    }
    // issue P5 B-frags before the barrier (latency hides)
    bf16x8 bw5[4];
#pragma unroll
    for (int ks = 0; ks < 4; ++ks)
      bw5[ks] = *(const bf16x8*)(wqb + WOT_E + (((ks << 2) + wave) * 64 + lane) * 8);
    __syncthreads();  // BARRIER_B: HG ready; XS(ch1) ready

    // ================= P5: out = HG @ w_out + b_out =================
    {
      bf16x8 ah[2][4];
#pragma unroll
      for (int mt = 0; mt < 2; ++mt)
#pragma unroll
        for (int ks = 0; ks < 4; ++ks)
          ah[mt][ks] = *(const bf16x8*)(HG + (mt * 16 + lr) * 136 + ks * 32 + lk);
      const f32x4 zz = {0.f, 0.f, 0.f, 0.f};
      f32x4 a5[2] = {zz, zz};
#pragma unroll
      for (int ks = 0; ks < 4; ++ks)
#pragma unroll
        for (int mt = 0; mt < 2; ++mt)
          a5[mt] = __builtin_amdgcn_mfma_f32_16x16x32_bf16(ah[mt][ks], bw5[ks], a5[mt], 0, 0, 0);
      size_t ob = (((size_t)bb * 64 + ch * 32) * 1024 + nn) * 64 + wave * 16 + lr;
#pragma unroll
      for (int mt = 0; mt < 2; ++mt)
#pragma unroll
        for (int r = 0; r < 4; ++r)
          out[ob + (size_t)(mt * 16 + lg * 4 + r) * 65536] = a5[mt][r] + bout;
    }
  }
}

extern "C" void kernel_launch(void* const* d_in, const int* in_sizes, int n_in,
                              void* d_out, int out_size, void* d_ws, size_t ws_size,
                              hipStream_t stream) {
  const float* x = (const float*)d_in[0];
  const float* w_in = (const float*)d_in[1];
  const float* b_in = (const float*)d_in[2];
  const float* w_conv = (const float*)d_in[3];
  const float* b_conv = (const float*)d_in[4];
  const float* w_delta = (const float*)d_in[5];
  const float* b_delta = (const float*)d_in[6];
  const float* w_si = (const float*)d_in[7];
  const float* b_si = (const float*)d_in[8];
  const float* w_so = (const float*)d_in[9];
  const float* b_so = (const float*)d_in[10];
  const float* a_log = (const float*)d_in[11];
  const float* d_skip = (const float*)d_in[12];
  const float* w_out = (const float*)d_in[13];
  const float* b_out = (const float*)d_in[14];

  __bf16* wq = (__bf16*)d_ws;
  float* a_s = (float*)((char*)d_ws + AS_BYTE);

  hipLaunchKernelGGL(prep_kernel, dim3(289), dim3(256), 0, stream,
                     w_in, w_delta, w_si, w_so, w_out, a_log, wq, a_s);
  hipLaunchKernelGGL(mamba_main, dim3(4096), dim3(256), 0, stream,
                     x, b_in, w_conv, b_conv, b_delta, b_si, b_so, d_skip, b_out,
                     wq, a_s, (float*)d_out);
}